// Round 1
// 426.840 us; speedup vs baseline: 1.0477x; 1.0477x over previous
//
#include <hip/hip_runtime.h>
#include <hip/hip_bf16.h>
#include <math.h>

// Problem constants
#define BB 16
#define NN 1024
#define EE 1024
#define HH 16
#define DD 64
#define THREE_E 3072
#define M_TOTAL (BB * NN)   // 16384

typedef __attribute__((ext_vector_type(8))) short bf16x8;   // 8 bf16 = 4 VGPR
typedef __attribute__((ext_vector_type(4))) short bf16x4;   // 4 bf16 = 2 VGPR
typedef __attribute__((ext_vector_type(4))) float floatx4;  // MFMA C/D

// Q pre-scale: 1/sqrt(64) * log2(e)  (scores land in exp2 domain)
#define SCALE_Q 0.18033688011112042f

static __device__ __forceinline__ unsigned short f2bf(float f) {
    union { float f; unsigned u; } x; x.f = f;
    unsigned r = x.u + 0x7fffu + ((x.u >> 16) & 1u);
    return (unsigned short)(r >> 16);
}

// pack 2x floatx4 -> bf16x8 via v_cvt_pk_bf16_f32 (RNE)
static __device__ __forceinline__ bf16x8 pack8v(floatx4 a, floatx4 b) {
    union { bf16x8 v; unsigned u[4]; } r;
    __hip_bfloat162 t;
    t = __float22bfloat162_rn(make_float2(a[0], a[1])); r.u[0] = *(unsigned*)&t;
    t = __float22bfloat162_rn(make_float2(a[2], a[3])); r.u[1] = *(unsigned*)&t;
    t = __float22bfloat162_rn(make_float2(b[0], b[1])); r.u[2] = *(unsigned*)&t;
    t = __float22bfloat162_rn(make_float2(b[2], b[3])); r.u[3] = *(unsigned*)&t;
    return r.v;
}
static __device__ __forceinline__ bf16x8 pack8f(float4 a, float4 b) {
    union { bf16x8 v; unsigned u[4]; } r;
    __hip_bfloat162 t;
    t = __float22bfloat162_rn(make_float2(a.x, a.y)); r.u[0] = *(unsigned*)&t;
    t = __float22bfloat162_rn(make_float2(a.z, a.w)); r.u[1] = *(unsigned*)&t;
    t = __float22bfloat162_rn(make_float2(b.x, b.y)); r.u[2] = *(unsigned*)&t;
    t = __float22bfloat162_rn(make_float2(b.z, b.w)); r.u[3] = *(unsigned*)&t;
    return r.v;
}

// async global->LDS, 16B per lane
#define ASYNC16(gp, lp)                                                \
    __builtin_amdgcn_global_load_lds(                                  \
        (const __attribute__((address_space(1))) void*)(gp),           \
        (__attribute__((address_space(3))) void*)(lp), 16, 0, 0)

// ---------------------------------------------------------------------------
// Prep 1: x fp32 [M,K] -> bf16 same layout.
// ---------------------------------------------------------------------------
__global__ __launch_bounds__(256) void convert_x(
    const float* __restrict__ x, unsigned short* __restrict__ xb)
{
    int i = blockIdx.x * 256 + threadIdx.x;
    const float4* xp = (const float4*)x;
    float4 a = xp[i * 2], b = xp[i * 2 + 1];
    *(bf16x8*)&xb[i * 8] = pack8f(a, b);
}

// ---------------------------------------------------------------------------
// Prep 2: transpose-convert W [R][C] fp32 -> bf16 [C][R].
// ---------------------------------------------------------------------------
__global__ __launch_bounds__(256) void wtrans(
    const float* __restrict__ w, unsigned short* __restrict__ wt, int R, int C)
{
    __shared__ float tile[32][33];
    const int t = threadIdx.x;
    const int lr = t >> 5, lc = t & 31;
    const int r0 = blockIdx.y * 32, c0 = blockIdx.x * 32;
    #pragma unroll
    for (int p = 0; p < 4; ++p)
        tile[lr + p * 8][lc] = w[(size_t)(r0 + lr + p * 8) * C + c0 + lc];
    __syncthreads();
    #pragma unroll
    for (int p = 0; p < 4; ++p) {
        int oc = lr + p * 8;
        float v = tile[lc][oc];
        wt[(size_t)(c0 + oc) * R + r0 + lc] = f2bf(v);
    }
}

// ---------------------------------------------------------------------------
// Kernel 1: qkv = xb @ Wqkv^T + b.
// 256x256 tile, BK=32, 8 waves (2x4), 4-deep circular LDS pipeline,
// counted vmcnt(8) (never 0 in main loop), 2 phases x 16 MFMA per K-step,
// setprio around MFMA clusters, raw s_barrier (no __syncthreads drain).
// LDS chunk-swizzle identical to verified 128^2 kernel: sigma(r)=((r^(r>>2))&3).
// ---------------------------------------------------------------------------
#define GNT 32   // K tiles: 1024 / 32

__global__ __launch_bounds__(512, 2) void gemm_qkv_mfma(
    const unsigned short* __restrict__ xb,
    const unsigned short* __restrict__ wt,
    const float* __restrict__ bias,
    unsigned short* __restrict__ Qo, unsigned short* __restrict__ Ko,
    unsigned short* __restrict__ Vo)
{
    __shared__ __align__(16) unsigned short As[4][256 * 32];  // 64 KB
    __shared__ __align__(16) unsigned short Bs[4][256 * 32];  // 64 KB

    const int t = threadIdx.x;
    const int w = t >> 6, lane = t & 63;
    const int quad = lane >> 4, l15 = lane & 15;
    const int wm = w >> 2, wn = w & 3;          // 2 x 4 wave grid

    // bijective XCD swizzle (gridDim.x % 8 == 0)
    const int id  = blockIdx.x;
    const int sid = (id & 7) * ((int)gridDim.x >> 3) + (id >> 3);
    const int m0 = (sid / 12) * 256;
    const int n0 = (sid % 12) * 256;

    const int srow = lane >> 2;
    const int scw = (((lane & 3) ^ ((srow ^ (srow >> 2)) & 3))) * 8;
    const int rsw = ((quad ^ ((l15 ^ (l15 >> 2)) & 3))) * 8;

    // per-lane pre-swizzled global sources; wave-uniform LDS bases
    const unsigned short* aG = &xb[(size_t)(m0 + w * 16 + srow) * EE + scw];
    const unsigned short* bG = &wt[(size_t)(n0 + w * 16 + srow) * EE + scw];
    const int ldsW = (w * 16) * 32;

#define STG_A(c) do { const int sl_ = (c) & 3;                          \
    ASYNC16(aG + (c) * 32,            &As[sl_][ldsW]);                  \
    ASYNC16(aG + (c) * 32 + 128 * EE, &As[sl_][ldsW + 128 * 32]); } while (0)
#define STG_B(c) do { const int sl_ = (c) & 3;                          \
    ASYNC16(bG + (c) * 32,            &Bs[sl_][ldsW]);                  \
    ASYNC16(bG + (c) * 32 + 128 * EE, &Bs[sl_][ldsW + 128 * 32]); } while (0)

    floatx4 acc[8][4];
    #pragma unroll
    for (int i = 0; i < 8; ++i)
        #pragma unroll
        for (int j = 0; j < 4; ++j) acc[i][j] = (floatx4){0.f, 0.f, 0.f, 0.f};

    // prologue: 3 tiles in flight; tile 0 guaranteed by vmcnt(8)
    STG_A(0); STG_B(0); STG_A(1); STG_B(1); STG_A(2); STG_B(2);
    __asm__ __volatile__("s_waitcnt vmcnt(8)" ::: "memory");
    __builtin_amdgcn_s_barrier();

    #pragma unroll 1
    for (int c = 0; c < GNT; ++c) {
        const unsigned short* Asl = As[c & 3];
        const unsigned short* Bsl = Bs[c & 3];
        bf16x8 bfr[4], afr[4];

        // ---- phase 0: rows wm*128 + [0,64) ----
        #pragma unroll
        for (int j = 0; j < 4; ++j)
            bfr[j] = *(const bf16x8*)&Bsl[(wn * 64 + j * 16 + l15) * 32 + rsw];
        #pragma unroll
        for (int i = 0; i < 4; ++i)
            afr[i] = *(const bf16x8*)&Asl[(wm * 128 + i * 16 + l15) * 32 + rsw];
        if (c + 3 < GNT) STG_A(c + 3);     // slot (c-1)&3: readers done last step
        __builtin_amdgcn_s_barrier();
        __asm__ __volatile__("s_waitcnt lgkmcnt(0)" ::: "memory");
        __builtin_amdgcn_s_setprio(1);
        #pragma unroll
        for (int i = 0; i < 4; ++i)
            #pragma unroll
            for (int j = 0; j < 4; ++j)
                acc[i][j] = __builtin_amdgcn_mfma_f32_16x16x32_bf16(
                    afr[i], bfr[j], acc[i][j], 0, 0, 0);
        __builtin_amdgcn_s_setprio(0);
        __builtin_amdgcn_s_barrier();

        // ---- phase 1: rows wm*128 + [64,128) (B frags reused) ----
        #pragma unroll
        for (int i = 0; i < 4; ++i)
            afr[i] = *(const bf16x8*)&Asl[(wm * 128 + 64 + i * 16 + l15) * 32 + rsw];
        if (c + 3 < GNT) STG_B(c + 3);
        __builtin_amdgcn_s_barrier();
        __asm__ __volatile__("s_waitcnt lgkmcnt(0)" ::: "memory");
        __builtin_amdgcn_s_setprio(1);
        #pragma unroll
        for (int i = 0; i < 4; ++i)
            #pragma unroll
            for (int j = 0; j < 4; ++j)
                acc[4 + i][j] = __builtin_amdgcn_mfma_f32_16x16x32_bf16(
                    afr[i], bfr[j], acc[4 + i][j], 0, 0, 0);
        __builtin_amdgcn_s_setprio(0);
        // counted drain: tile c+1 guaranteed, 2 tiles (8 loads) stay in flight
        if (c < GNT - 3)       { __asm__ __volatile__("s_waitcnt vmcnt(8)" ::: "memory"); }
        else if (c == GNT - 3) { __asm__ __volatile__("s_waitcnt vmcnt(4)" ::: "memory"); }
        else if (c == GNT - 2) { __asm__ __volatile__("s_waitcnt vmcnt(0)" ::: "memory"); }
        __builtin_amdgcn_s_barrier();
    }
#undef STG_A
#undef STG_B

    // epilogue: Q,K,V written natural [B,H,N,D]; `which` is block-uniform
    const int mb = m0 + wm * 128;
    const int nbase = n0 + wn * 64;
    #pragma unroll
    for (int i = 0; i < 8; ++i) {
        #pragma unroll
        for (int j = 0; j < 4; ++j) {
            int nc = nbase + j * 16;
            int which = nc >> 10;
            int e0 = nc & 1023;
            int h  = e0 >> 6;
            int d0 = e0 & 63;
            float bv = bias[nc + l15];
            #pragma unroll
            for (int r = 0; r < 4; ++r) {
                int m = mb + i * 16 + quad * 4 + r;
                int b = m >> 10, n = m & 1023;
                size_t off = ((size_t)(b * HH + h) * NN + n) * DD + d0 + l15;
                float v = acc[i][j][r] + bv;
                if (which == 0)      Qo[off] = f2bf(v * SCALE_Q);
                else if (which == 1) Ko[off] = f2bf(v);
                else                 Vo[off] = f2bf(v);
            }
        }
    }
}

// ---------------------------------------------------------------------------
// Prep 3 (post-qkv): V [B,H,N,D] bf16 -> Vt [B,H,D,N] bf16.
// ---------------------------------------------------------------------------
__global__ __launch_bounds__(256) void vtrans(
    const unsigned short* __restrict__ V, unsigned short* __restrict__ Vt)
{
    __shared__ __align__(16) unsigned short tile[64][72];   // [d][n]
    const int t  = threadIdx.x;
    const int bh = blockIdx.x;       // 0..255
    const int n0 = blockIdx.y * 64;  // 16 tiles
    const int r  = t >> 2, c = t & 3;

    const unsigned short* src = &V[((size_t)bh * NN + n0 + r) * DD + c * 16];
    bf16x8 v0 = *(const bf16x8*)&src[0];
    bf16x8 v1 = *(const bf16x8*)&src[8];
    #pragma unroll
    for (int k = 0; k < 8; ++k) tile[c * 16 + k][r]     = v0[k];
    #pragma unroll
    for (int k = 0; k < 8; ++k) tile[c * 16 + 8 + k][r] = v1[k];
    __syncthreads();

    unsigned short* dst = &Vt[((size_t)bh * DD + r) * NN + n0 + c * 16];
    *(bf16x8*)&dst[0] = *(const bf16x8*)&tile[r][c * 16];
    *(bf16x8*)&dst[8] = *(const bf16x8*)&tile[r][c * 16 + 8];
}

// ---------------------------------------------------------------------------
// Kernel 2: transposed-score flash attention, bf16 MFMA (unchanged).
// ---------------------------------------------------------------------------
__global__ __launch_bounds__(256) void attn_mfma(
    const unsigned short* __restrict__ Q,
    const unsigned short* __restrict__ K,
    const unsigned short* __restrict__ Vt,
    unsigned short* __restrict__ O)
{
    __shared__ __align__(16) unsigned short Ks[64 * 64];  // [key][d], swizzled
    __shared__ __align__(16) unsigned short Vs[64 * 64];  // [d][kappa], swizzled

    const int t    = threadIdx.x;
    const int w    = t >> 6;
    const int quad = (t >> 4) & 3;
    const int l15  = t & 15;
    const int i    = blockIdx.x;                 // 0..2047
    const int bh   = ((i >> 6) << 3) | (i & 7);  // XCD-local bh windows
    const int qt   = (i >> 3) & 7;

    const unsigned short* Qg = Q  + (size_t)bh * NN * DD;
    const unsigned short* Kg = K  + (size_t)bh * NN * DD;
    const unsigned short* Vg = Vt + (size_t)bh * DD * NN;

    const int q0 = qt * 128 + w * 32;

    bf16x8 qf[2][2];
    #pragma unroll
    for (int a = 0; a < 2; ++a) {
        qf[a][0] = *(const bf16x8*)&Qg[(size_t)(q0 + a * 16 + l15) * DD + quad * 8];
        qf[a][1] = *(const bf16x8*)&Qg[(size_t)(q0 + a * 16 + l15) * DD + 32 + quad * 8];
    }

    floatx4 oa[2][4];
    #pragma unroll
    for (int a = 0; a < 2; ++a)
        #pragma unroll
        for (int jd = 0; jd < 4; ++jd) oa[a][jd] = (floatx4){0.f, 0.f, 0.f, 0.f};
    float lsum[2] = {0.f, 0.f};

    const int srow = t >> 2;
    const int sc   = t & 3;
    const int swz  = srow & 7;
    const int cbase = ((quad ^ (l15 & 7)) << 3);

    bf16x8 kr0, kr1, vr0, vr1;
    {
        const unsigned short* kg = &Kg[(size_t)srow * DD + sc * 16];
        kr0 = *(const bf16x8*)&kg[0];
        kr1 = *(const bf16x8*)&kg[8];
        const unsigned short* vg = &Vg[(size_t)srow * NN + sc * 16];
        vr0 = *(const bf16x8*)&vg[0];
        vr1 = *(const bf16x8*)&vg[8];
    }

    for (int kt = 0; kt < 16; ++kt) {
        __syncthreads();
        *(bf16x8*)&Ks[srow * 64 + (((2 * sc + 0) ^ swz) << 3)] = kr0;
        *(bf16x8*)&Ks[srow * 64 + (((2 * sc + 1) ^ swz) << 3)] = kr1;
        {
            bf16x4 h[4];
            h[0] = (bf16x4){vr0[0], vr0[1], vr0[2], vr0[3]};
            h[1] = (bf16x4){vr0[4], vr0[5], vr0[6], vr0[7]};
            h[2] = (bf16x4){vr1[0], vr1[1], vr1[2], vr1[3]};
            h[3] = (bf16x4){vr1[4], vr1[5], vr1[6], vr1[7]};
            #pragma unroll
            for (int q = 0; q < 4; ++q) {
                int col = ((((sc >> 1) * 4 + q) ^ swz) << 3) + ((sc & 1) << 2);
                *(bf16x4*)&Vs[srow * 64 + col] = h[q];
            }
        }
        __syncthreads();

        if (kt < 15) {
            const unsigned short* kg =
                &Kg[(size_t)((kt + 1) * 64 + srow) * DD + sc * 16];
            kr0 = *(const bf16x8*)&kg[0];
            kr1 = *(const bf16x8*)&kg[8];
            const unsigned short* vg =
                &Vg[(size_t)srow * NN + (kt + 1) * 64 + sc * 16];
            vr0 = *(const bf16x8*)&vg[0];
            vr1 = *(const bf16x8*)&vg[8];
        }

        floatx4 sa[2][4];
        #pragma unroll
        for (int a = 0; a < 2; ++a)
            #pragma unroll
            for (int tt = 0; tt < 4; ++tt) sa[a][tt] = (floatx4){0.f, 0.f, 0.f, 0.f};
        #pragma unroll
        for (int tt = 0; tt < 4; ++tt) {
            const unsigned short* kb = &Ks[(tt * 16 + l15) * 64];
            bf16x8 kf0 = *(const bf16x8*)&kb[cbase];
            bf16x8 kf1 = *(const bf16x8*)&kb[cbase ^ 32];
            #pragma unroll
            for (int a = 0; a < 2; ++a) {
                sa[a][tt] = __builtin_amdgcn_mfma_f32_16x16x32_bf16(
                    kf0, qf[a][0], sa[a][tt], 0, 0, 0);
                sa[a][tt] = __builtin_amdgcn_mfma_f32_16x16x32_bf16(
                    kf1, qf[a][1], sa[a][tt], 0, 0, 0);
            }
        }

        bf16x8 pf[2][2];
        #pragma unroll
        for (int a = 0; a < 2; ++a) {
            floatx4 pe[4];
            #pragma unroll
            for (int tt = 0; tt < 4; ++tt) {
                #pragma unroll
                for (int r = 0; r < 4; ++r) {
                    float p = exp2f(sa[a][tt][r]);
                    pe[tt][r] = p;
                    lsum[a] += p;
                }
            }
            pf[a][0] = pack8v(pe[0], pe[1]);
            pf[a][1] = pack8v(pe[2], pe[3]);
        }

        #pragma unroll
        for (int jd = 0; jd < 4; ++jd) {
            const unsigned short* vb = &Vs[(jd * 16 + l15) * 64];
            bf16x8 vf0 = *(const bf16x8*)&vb[cbase];
            bf16x8 vf1 = *(const bf16x8*)&vb[cbase ^ 32];
            #pragma unroll
            for (int a = 0; a < 2; ++a) {
                oa[a][jd] = __builtin_amdgcn_mfma_f32_16x16x32_bf16(
                    vf0, pf[a][0], oa[a][jd], 0, 0, 0);
                oa[a][jd] = __builtin_amdgcn_mfma_f32_16x16x32_bf16(
                    vf1, pf[a][1], oa[a][jd], 0, 0, 0);
            }
        }
    }

    #pragma unroll
    for (int a = 0; a < 2; ++a) {
        lsum[a] += __shfl_xor(lsum[a], 16, 64);
        lsum[a] += __shfl_xor(lsum[a], 32, 64);
    }

    const int b = bh >> 4, h = bh & 15;
    #pragma unroll
    for (int a = 0; a < 2; ++a) {
        float inv = 1.f / lsum[a];
        int n = q0 + a * 16 + l15;
        size_t base = (size_t)(b * NN + n) * EE + h * DD;
        #pragma unroll
        for (int jd = 0; jd < 4; ++jd) {
            bf16x4 v;
            v[0] = (short)f2bf(oa[a][jd][0] * inv);
            v[1] = (short)f2bf(oa[a][jd][1] * inv);
            v[2] = (short)f2bf(oa[a][jd][2] * inv);
            v[3] = (short)f2bf(oa[a][jd][3] * inv);
            *(bf16x4*)&O[base + jd * 16 + quad * 4] = v;
        }
    }
}

// ---------------------------------------------------------------------------
// Kernel 3: out = O @ Wp^T + b — same 256^2 pipelined structure, fp32 out.
// ---------------------------------------------------------------------------
__global__ __launch_bounds__(512, 2) void gemm_proj_mfma(
    const unsigned short* __restrict__ Ob,
    const unsigned short* __restrict__ Bp,
    const float* __restrict__ bias, float* __restrict__ out)
{
    __shared__ __align__(16) unsigned short As[4][256 * 32];
    __shared__ __align__(16) unsigned short Bs[4][256 * 32];

    const int t = threadIdx.x;
    const int w = t >> 6, lane = t & 63;
    const int quad = lane >> 4, l15 = lane & 15;
    const int wm = w >> 2, wn = w & 3;

    const int id  = blockIdx.x;
    const int sid = (id & 7) * ((int)gridDim.x >> 3) + (id >> 3);
    const int m0 = (sid / 4) * 256;
    const int n0 = (sid % 4) * 256;

    const int srow = lane >> 2;
    const int scw = (((lane & 3) ^ ((srow ^ (srow >> 2)) & 3))) * 8;
    const int rsw = ((quad ^ ((l15 ^ (l15 >> 2)) & 3))) * 8;

    const unsigned short* aG = &Ob[(size_t)(m0 + w * 16 + srow) * EE + scw];
    const unsigned short* bG = &Bp[(size_t)(n0 + w * 16 + srow) * EE + scw];
    const int ldsW = (w * 16) * 32;

#define STG_A(c) do { const int sl_ = (c) & 3;                          \
    ASYNC16(aG + (c) * 32,            &As[sl_][ldsW]);                  \
    ASYNC16(aG + (c) * 32 + 128 * EE, &As[sl_][ldsW + 128 * 32]); } while (0)
#define STG_B(c) do { const int sl_ = (c) & 3;                          \
    ASYNC16(bG + (c) * 32,            &Bs[sl_][ldsW]);                  \
    ASYNC16(bG + (c) * 32 + 128 * EE, &Bs[sl_][ldsW + 128 * 32]); } while (0)

    floatx4 acc[8][4];
    #pragma unroll
    for (int i = 0; i < 8; ++i)
        #pragma unroll
        for (int j = 0; j < 4; ++j) acc[i][j] = (floatx4){0.f, 0.f, 0.f, 0.f};

    STG_A(0); STG_B(0); STG_A(1); STG_B(1); STG_A(2); STG_B(2);
    __asm__ __volatile__("s_waitcnt vmcnt(8)" ::: "memory");
    __builtin_amdgcn_s_barrier();

    #pragma unroll 1
    for (int c = 0; c < GNT; ++c) {
        const unsigned short* Asl = As[c & 3];
        const unsigned short* Bsl = Bs[c & 3];
        bf16x8 bfr[4], afr[4];

        #pragma unroll
        for (int j = 0; j < 4; ++j)
            bfr[j] = *(const bf16x8*)&Bsl[(wn * 64 + j * 16 + l15) * 32 + rsw];
        #pragma unroll
        for (int i = 0; i < 4; ++i)
            afr[i] = *(const bf16x8*)&Asl[(wm * 128 + i * 16 + l15) * 32 + rsw];
        if (c + 3 < GNT) STG_A(c + 3);
        __builtin_amdgcn_s_barrier();
        __asm__ __volatile__("s_waitcnt lgkmcnt(0)" ::: "memory");
        __builtin_amdgcn_s_setprio(1);
        #pragma unroll
        for (int i = 0; i < 4; ++i)
            #pragma unroll
            for (int j = 0; j < 4; ++j)
                acc[i][j] = __builtin_amdgcn_mfma_f32_16x16x32_bf16(
                    afr[i], bfr[j], acc[i][j], 0, 0, 0);
        __builtin_amdgcn_s_setprio(0);
        __builtin_amdgcn_s_barrier();

        #pragma unroll
        for (int i = 0; i < 4; ++i)
            afr[i] = *(const bf16x8*)&Asl[(wm * 128 + 64 + i * 16 + l15) * 32 + rsw];
        if (c + 3 < GNT) STG_B(c + 3);
        __builtin_amdgcn_s_barrier();
        __asm__ __volatile__("s_waitcnt lgkmcnt(0)" ::: "memory");
        __builtin_amdgcn_s_setprio(1);
        #pragma unroll
        for (int i = 0; i < 4; ++i)
            #pragma unroll
            for (int j = 0; j < 4; ++j)
                acc[4 + i][j] = __builtin_amdgcn_mfma_f32_16x16x32_bf16(
                    afr[i], bfr[j], acc[4 + i][j], 0, 0, 0);
        __builtin_amdgcn_s_setprio(0);
        if (c < GNT - 3)       { __asm__ __volatile__("s_waitcnt vmcnt(8)" ::: "memory"); }
        else if (c == GNT - 3) { __asm__ __volatile__("s_waitcnt vmcnt(4)" ::: "memory"); }
        else if (c == GNT - 2) { __asm__ __volatile__("s_waitcnt vmcnt(0)" ::: "memory"); }
        __builtin_amdgcn_s_barrier();
    }
#undef STG_A
#undef STG_B

    const int mb = m0 + wm * 128;
    const int nbase = n0 + wn * 64;
    #pragma unroll
    for (int i = 0; i < 8; ++i) {
        #pragma unroll
        for (int j = 0; j < 4; ++j) {
            float bv = bias[nbase + j * 16 + l15];
            #pragma unroll
            for (int r = 0; r < 4; ++r) {
                int mrow = mb + i * 16 + quad * 4 + r;
                out[(size_t)mrow * EE + nbase + j * 16 + l15] = acc[i][j][r] + bv;
            }
        }
    }
}

// ---------------------------------------------------------------------------
extern "C" void kernel_launch(void* const* d_in, const int* in_sizes, int n_in,
                              void* d_out, int out_size, void* d_ws, size_t ws_size,
                              hipStream_t stream) {
    const float* x     = (const float*)d_in[0];
    const float* Wqkv  = (const float*)d_in[1];
    const float* bqkv  = (const float*)d_in[2];
    const float* Wproj = (const float*)d_in[3];
    const float* bproj = (const float*)d_in[4];
    float* out = (float*)d_out;

    const size_t BHND = (size_t)BB * HH * NN * DD;      // 16777216
    unsigned short* Q   = (unsigned short*)d_ws;
    unsigned short* K   = Q   + BHND;
    unsigned short* Vn  = K   + BHND;                   // V natural [B,H,N,D]
    unsigned short* Vt  = Vn  + BHND;                   // V^T [B,H,D,N]
    unsigned short* Ob  = Vt  + BHND;                   // [16384][1024] bf16
    unsigned short* xb  = Ob  + BHND;
    unsigned short* Wqt = xb  + BHND;                   // [3072][1024]
    unsigned short* Wpt = Wqt + (size_t)THREE_E * EE;   // [1024][1024]

    dim3 blk(256);
    convert_x<<<dim3(M_TOTAL * EE / (256 * 8)), blk, 0, stream>>>(x, xb);
    wtrans<<<dim3(THREE_E / 32, EE / 32), blk, 0, stream>>>(Wqkv, Wqt, EE, THREE_E);
    wtrans<<<dim3(EE / 32, EE / 32), blk, 0, stream>>>(Wproj, Wpt, EE, EE);

    gemm_qkv_mfma<<<dim3((M_TOTAL / 256) * (THREE_E / 256)), dim3(512), 0, stream>>>(
        xb, Wqt, bqkv, Q, K, Vn);
    vtrans<<<dim3(BB * HH, NN / 64), blk, 0, stream>>>(Vn, Vt);
    attn_mfma<<<dim3(BB * HH * NN / 128), blk, 0, stream>>>(Q, K, Vt, Ob);
    gemm_proj_mfma<<<dim3((M_TOTAL / 256) * (EE / 256)), dim3(512), 0, stream>>>(
        Ob, Wpt, bproj, out);
}

// Round 2
// 405.373 us; speedup vs baseline: 1.1032x; 1.0530x over previous
//
#include <hip/hip_runtime.h>
#include <hip/hip_bf16.h>
#include <math.h>

// Problem constants
#define BB 16
#define NN 1024
#define EE 1024
#define HH 16
#define DD 64
#define THREE_E 3072
#define M_TOTAL (BB * NN)   // 16384

typedef __attribute__((ext_vector_type(8))) short bf16x8;   // 8 bf16 = 4 VGPR
typedef __attribute__((ext_vector_type(4))) short bf16x4;   // 4 bf16 = 2 VGPR
typedef __attribute__((ext_vector_type(4))) float floatx4;  // MFMA C/D

// Q pre-scale: 1/sqrt(64) * log2(e)  (scores land in exp2 domain)
#define SCALE_Q 0.18033688011112042f

static __device__ __forceinline__ unsigned short f2bf(float f) {
    union { float f; unsigned u; } x; x.f = f;
    unsigned r = x.u + 0x7fffu + ((x.u >> 16) & 1u);
    return (unsigned short)(r >> 16);
}

// raw v_exp_f32 — scores are bounded, skip OCML denormal guards
static __device__ __forceinline__ float fast_exp2(float x) {
#if __has_builtin(__builtin_amdgcn_exp2f)
    return __builtin_amdgcn_exp2f(x);
#else
    float r; __asm__("v_exp_f32 %0, %1" : "=v"(r) : "v"(x)); return r;
#endif
}

// pack 2x floatx4 -> bf16x8 via v_cvt_pk_bf16_f32 (RNE)
static __device__ __forceinline__ bf16x8 pack8v(floatx4 a, floatx4 b) {
    union { bf16x8 v; unsigned u[4]; } r;
    __hip_bfloat162 t;
    t = __float22bfloat162_rn(make_float2(a[0], a[1])); r.u[0] = *(unsigned*)&t;
    t = __float22bfloat162_rn(make_float2(a[2], a[3])); r.u[1] = *(unsigned*)&t;
    t = __float22bfloat162_rn(make_float2(b[0], b[1])); r.u[2] = *(unsigned*)&t;
    t = __float22bfloat162_rn(make_float2(b[2], b[3])); r.u[3] = *(unsigned*)&t;
    return r.v;
}
static __device__ __forceinline__ bf16x8 pack8f(float4 a, float4 b) {
    union { bf16x8 v; unsigned u[4]; } r;
    __hip_bfloat162 t;
    t = __float22bfloat162_rn(make_float2(a.x, a.y)); r.u[0] = *(unsigned*)&t;
    t = __float22bfloat162_rn(make_float2(a.z, a.w)); r.u[1] = *(unsigned*)&t;
    t = __float22bfloat162_rn(make_float2(b.x, b.y)); r.u[2] = *(unsigned*)&t;
    t = __float22bfloat162_rn(make_float2(b.z, b.w)); r.u[3] = *(unsigned*)&t;
    return r.v;
}

// async global->LDS, 16B per lane
#define ASYNC16(gp, lp)                                                \
    __builtin_amdgcn_global_load_lds(                                  \
        (const __attribute__((address_space(1))) void*)(gp),           \
        (__attribute__((address_space(3))) void*)(lp), 16, 0, 0)

// ---------------------------------------------------------------------------
// Prep 1: x fp32 [M,K] -> bf16 same layout.
// ---------------------------------------------------------------------------
__global__ __launch_bounds__(256) void convert_x(
    const float* __restrict__ x, unsigned short* __restrict__ xb)
{
    int i = blockIdx.x * 256 + threadIdx.x;
    const float4* xp = (const float4*)x;
    float4 a = xp[i * 2], b = xp[i * 2 + 1];
    *(bf16x8*)&xb[i * 8] = pack8f(a, b);
}

// ---------------------------------------------------------------------------
// Prep 2: transpose-convert W [R][C] fp32 -> bf16 [C][R].
// ---------------------------------------------------------------------------
__global__ __launch_bounds__(256) void wtrans(
    const float* __restrict__ w, unsigned short* __restrict__ wt, int R, int C)
{
    __shared__ float tile[32][33];
    const int t = threadIdx.x;
    const int lr = t >> 5, lc = t & 31;
    const int r0 = blockIdx.y * 32, c0 = blockIdx.x * 32;
    #pragma unroll
    for (int p = 0; p < 4; ++p)
        tile[lr + p * 8][lc] = w[(size_t)(r0 + lr + p * 8) * C + c0 + lc];
    __syncthreads();
    #pragma unroll
    for (int p = 0; p < 4; ++p) {
        int oc = lr + p * 8;
        float v = tile[lc][oc];
        wt[(size_t)(c0 + oc) * R + r0 + lc] = f2bf(v);
    }
}

// ---------------------------------------------------------------------------
// Kernel 1: qkv = xb @ Wqkv^T + b.
// 256x256 tile, BK=32, 8 waves (2x4), 4-deep circular LDS pipeline,
// counted vmcnt(8) (never 0 in main loop), 2 phases x 16 MFMA per K-step,
// setprio around MFMA clusters, raw s_barrier (no __syncthreads drain).
// ---------------------------------------------------------------------------
#define GNT 32   // K tiles: 1024 / 32

__global__ __launch_bounds__(512, 2) void gemm_qkv_mfma(
    const unsigned short* __restrict__ xb,
    const unsigned short* __restrict__ wt,
    const float* __restrict__ bias,
    unsigned short* __restrict__ Qo, unsigned short* __restrict__ Ko,
    unsigned short* __restrict__ Vo)
{
    __shared__ __align__(16) unsigned short As[4][256 * 32];  // 64 KB
    __shared__ __align__(16) unsigned short Bs[4][256 * 32];  // 64 KB

    const int t = threadIdx.x;
    const int w = t >> 6, lane = t & 63;
    const int quad = lane >> 4, l15 = lane & 15;
    const int wm = w >> 2, wn = w & 3;          // 2 x 4 wave grid

    // bijective XCD swizzle (gridDim.x % 8 == 0)
    const int id  = blockIdx.x;
    const int sid = (id & 7) * ((int)gridDim.x >> 3) + (id >> 3);
    const int m0 = (sid / 12) * 256;
    const int n0 = (sid % 12) * 256;

    const int srow = lane >> 2;
    const int scw = (((lane & 3) ^ ((srow ^ (srow >> 2)) & 3))) * 8;
    const int rsw = ((quad ^ ((l15 ^ (l15 >> 2)) & 3))) * 8;

    // per-lane pre-swizzled global sources; wave-uniform LDS bases
    const unsigned short* aG = &xb[(size_t)(m0 + w * 16 + srow) * EE + scw];
    const unsigned short* bG = &wt[(size_t)(n0 + w * 16 + srow) * EE + scw];
    const int ldsW = (w * 16) * 32;

#define STG_A(c) do { const int sl_ = (c) & 3;                          \
    ASYNC16(aG + (c) * 32,            &As[sl_][ldsW]);                  \
    ASYNC16(aG + (c) * 32 + 128 * EE, &As[sl_][ldsW + 128 * 32]); } while (0)
#define STG_B(c) do { const int sl_ = (c) & 3;                          \
    ASYNC16(bG + (c) * 32,            &Bs[sl_][ldsW]);                  \
    ASYNC16(bG + (c) * 32 + 128 * EE, &Bs[sl_][ldsW + 128 * 32]); } while (0)

    floatx4 acc[8][4];
    #pragma unroll
    for (int i = 0; i < 8; ++i)
        #pragma unroll
        for (int j = 0; j < 4; ++j) acc[i][j] = (floatx4){0.f, 0.f, 0.f, 0.f};

    // prologue: 3 tiles in flight; tile 0 guaranteed by vmcnt(8)
    STG_A(0); STG_B(0); STG_A(1); STG_B(1); STG_A(2); STG_B(2);
    __asm__ __volatile__("s_waitcnt vmcnt(8)" ::: "memory");
    __builtin_amdgcn_s_barrier();

    #pragma unroll 1
    for (int c = 0; c < GNT; ++c) {
        const unsigned short* Asl = As[c & 3];
        const unsigned short* Bsl = Bs[c & 3];
        bf16x8 bfr[4], afr[4];

        // ---- phase 0: rows wm*128 + [0,64) ----
        #pragma unroll
        for (int j = 0; j < 4; ++j)
            bfr[j] = *(const bf16x8*)&Bsl[(wn * 64 + j * 16 + l15) * 32 + rsw];
        #pragma unroll
        for (int i = 0; i < 4; ++i)
            afr[i] = *(const bf16x8*)&Asl[(wm * 128 + i * 16 + l15) * 32 + rsw];
        if (c + 3 < GNT) STG_A(c + 3);     // slot (c-1)&3: readers done last step
        __builtin_amdgcn_s_barrier();
        __asm__ __volatile__("s_waitcnt lgkmcnt(0)" ::: "memory");
        __builtin_amdgcn_s_setprio(1);
        #pragma unroll
        for (int i = 0; i < 4; ++i)
            #pragma unroll
            for (int j = 0; j < 4; ++j)
                acc[i][j] = __builtin_amdgcn_mfma_f32_16x16x32_bf16(
                    afr[i], bfr[j], acc[i][j], 0, 0, 0);
        __builtin_amdgcn_s_setprio(0);
        __builtin_amdgcn_s_barrier();

        // ---- phase 1: rows wm*128 + [64,128) (B frags reused) ----
        #pragma unroll
        for (int i = 0; i < 4; ++i)
            afr[i] = *(const bf16x8*)&Asl[(wm * 128 + 64 + i * 16 + l15) * 32 + rsw];
        if (c + 3 < GNT) STG_B(c + 3);
        __builtin_amdgcn_s_barrier();
        __asm__ __volatile__("s_waitcnt lgkmcnt(0)" ::: "memory");
        __builtin_amdgcn_s_setprio(1);
        #pragma unroll
        for (int i = 0; i < 4; ++i)
            #pragma unroll
            for (int j = 0; j < 4; ++j)
                acc[4 + i][j] = __builtin_amdgcn_mfma_f32_16x16x32_bf16(
                    afr[i], bfr[j], acc[4 + i][j], 0, 0, 0);
        __builtin_amdgcn_s_setprio(0);
        // counted drain: tile c+1 guaranteed, 2 tiles (8 loads) stay in flight
        if (c < GNT - 3)       { __asm__ __volatile__("s_waitcnt vmcnt(8)" ::: "memory"); }
        else if (c == GNT - 3) { __asm__ __volatile__("s_waitcnt vmcnt(4)" ::: "memory"); }
        else if (c == GNT - 2) { __asm__ __volatile__("s_waitcnt vmcnt(0)" ::: "memory"); }
        __builtin_amdgcn_s_barrier();
    }
#undef STG_A
#undef STG_B

    // epilogue: Q,K,V written natural [B,H,N,D]; `which` is block-uniform
    const int mb = m0 + wm * 128;
    const int nbase = n0 + wn * 64;
    #pragma unroll
    for (int i = 0; i < 8; ++i) {
        #pragma unroll
        for (int j = 0; j < 4; ++j) {
            int nc = nbase + j * 16;
            int which = nc >> 10;
            int e0 = nc & 1023;
            int h  = e0 >> 6;
            int d0 = e0 & 63;
            float bv = bias[nc + l15];
            #pragma unroll
            for (int r = 0; r < 4; ++r) {
                int m = mb + i * 16 + quad * 4 + r;
                int b = m >> 10, n = m & 1023;
                size_t off = ((size_t)(b * HH + h) * NN + n) * DD + d0 + l15;
                float v = acc[i][j][r] + bv;
                if (which == 0)      Qo[off] = f2bf(v * SCALE_Q);
                else if (which == 1) Ko[off] = f2bf(v);
                else                 Vo[off] = f2bf(v);
            }
        }
    }
}

// ---------------------------------------------------------------------------
// Prep 3 (post-qkv): V [B,H,N,D] bf16 -> Vt [B,H,D,N] bf16.
// ---------------------------------------------------------------------------
__global__ __launch_bounds__(256) void vtrans(
    const unsigned short* __restrict__ V, unsigned short* __restrict__ Vt)
{
    __shared__ __align__(16) unsigned short tile[64][72];   // [d][n]
    const int t  = threadIdx.x;
    const int bh = blockIdx.x;       // 0..255
    const int n0 = blockIdx.y * 64;  // 16 tiles
    const int r  = t >> 2, c = t & 3;

    const unsigned short* src = &V[((size_t)bh * NN + n0 + r) * DD + c * 16];
    bf16x8 v0 = *(const bf16x8*)&src[0];
    bf16x8 v1 = *(const bf16x8*)&src[8];
    #pragma unroll
    for (int k = 0; k < 8; ++k) tile[c * 16 + k][r]     = v0[k];
    #pragma unroll
    for (int k = 0; k < 8; ++k) tile[c * 16 + 8 + k][r] = v1[k];
    __syncthreads();

    unsigned short* dst = &Vt[((size_t)bh * DD + r) * NN + n0 + c * 16];
    *(bf16x8*)&dst[0] = *(const bf16x8*)&tile[r][c * 16];
    *(bf16x8*)&dst[8] = *(const bf16x8*)&tile[r][c * 16 + 8];
}

// ---------------------------------------------------------------------------
// Kernel 2: transposed-score flash attention, bf16 MFMA.
// R2: raw v_exp_f32, MFMA-ones row-sum (kills serial add chain + final
// shuffles), setprio around MFMA clusters.
// ---------------------------------------------------------------------------
__global__ __launch_bounds__(256) void attn_mfma(
    const unsigned short* __restrict__ Q,
    const unsigned short* __restrict__ K,
    const unsigned short* __restrict__ Vt,
    unsigned short* __restrict__ O)
{
    __shared__ __align__(16) unsigned short Ks[64 * 64];  // [key][d], swizzled
    __shared__ __align__(16) unsigned short Vs[64 * 64];  // [d][kappa], swizzled

    const int t    = threadIdx.x;
    const int w    = t >> 6;
    const int quad = (t >> 4) & 3;
    const int l15  = t & 15;
    const int i    = blockIdx.x;                 // 0..2047
    const int bh   = ((i >> 6) << 3) | (i & 7);  // XCD-local bh windows
    const int qt   = (i >> 3) & 7;

    const unsigned short* Qg = Q  + (size_t)bh * NN * DD;
    const unsigned short* Kg = K  + (size_t)bh * NN * DD;
    const unsigned short* Vg = Vt + (size_t)bh * DD * NN;

    const int q0 = qt * 128 + w * 32;

    bf16x8 qf[2][2];
    #pragma unroll
    for (int a = 0; a < 2; ++a) {
        qf[a][0] = *(const bf16x8*)&Qg[(size_t)(q0 + a * 16 + l15) * DD + quad * 8];
        qf[a][1] = *(const bf16x8*)&Qg[(size_t)(q0 + a * 16 + l15) * DD + 32 + quad * 8];
    }

    // all-ones A-fragment: mfma(ones, P) -> every output element = column sum
    bf16x8 onesA;
    #pragma unroll
    for (int z = 0; z < 8; ++z) onesA[z] = (short)0x3F80;  // bf16 1.0

    floatx4 oa[2][4];
    #pragma unroll
    for (int a = 0; a < 2; ++a)
        #pragma unroll
        for (int jd = 0; jd < 4; ++jd) oa[a][jd] = (floatx4){0.f, 0.f, 0.f, 0.f};
    floatx4 ls[2];
    ls[0] = (floatx4){0.f, 0.f, 0.f, 0.f};
    ls[1] = (floatx4){0.f, 0.f, 0.f, 0.f};

    const int srow = t >> 2;
    const int sc   = t & 3;
    const int swz  = srow & 7;
    const int cbase = ((quad ^ (l15 & 7)) << 3);

    bf16x8 kr0, kr1, vr0, vr1;
    {
        const unsigned short* kg = &Kg[(size_t)srow * DD + sc * 16];
        kr0 = *(const bf16x8*)&kg[0];
        kr1 = *(const bf16x8*)&kg[8];
        const unsigned short* vg = &Vg[(size_t)srow * NN + sc * 16];
        vr0 = *(const bf16x8*)&vg[0];
        vr1 = *(const bf16x8*)&vg[8];
    }

    for (int kt = 0; kt < 16; ++kt) {
        __syncthreads();
        *(bf16x8*)&Ks[srow * 64 + (((2 * sc + 0) ^ swz) << 3)] = kr0;
        *(bf16x8*)&Ks[srow * 64 + (((2 * sc + 1) ^ swz) << 3)] = kr1;
        {
            bf16x4 h[4];
            h[0] = (bf16x4){vr0[0], vr0[1], vr0[2], vr0[3]};
            h[1] = (bf16x4){vr0[4], vr0[5], vr0[6], vr0[7]};
            h[2] = (bf16x4){vr1[0], vr1[1], vr1[2], vr1[3]};
            h[3] = (bf16x4){vr1[4], vr1[5], vr1[6], vr1[7]};
            #pragma unroll
            for (int q = 0; q < 4; ++q) {
                int col = ((((sc >> 1) * 4 + q) ^ swz) << 3) + ((sc & 1) << 2);
                *(bf16x4*)&Vs[srow * 64 + col] = h[q];
            }
        }
        __syncthreads();

        if (kt < 15) {
            const unsigned short* kg =
                &Kg[(size_t)((kt + 1) * 64 + srow) * DD + sc * 16];
            kr0 = *(const bf16x8*)&kg[0];
            kr1 = *(const bf16x8*)&kg[8];
            const unsigned short* vg =
                &Vg[(size_t)srow * NN + (kt + 1) * 64 + sc * 16];
            vr0 = *(const bf16x8*)&vg[0];
            vr1 = *(const bf16x8*)&vg[8];
        }

        floatx4 sa[2][4];
        #pragma unroll
        for (int a = 0; a < 2; ++a)
            #pragma unroll
            for (int tt = 0; tt < 4; ++tt) sa[a][tt] = (floatx4){0.f, 0.f, 0.f, 0.f};
        __builtin_amdgcn_s_setprio(1);
        #pragma unroll
        for (int tt = 0; tt < 4; ++tt) {
            const unsigned short* kb = &Ks[(tt * 16 + l15) * 64];
            bf16x8 kf0 = *(const bf16x8*)&kb[cbase];
            bf16x8 kf1 = *(const bf16x8*)&kb[cbase ^ 32];
            #pragma unroll
            for (int a = 0; a < 2; ++a) {
                sa[a][tt] = __builtin_amdgcn_mfma_f32_16x16x32_bf16(
                    kf0, qf[a][0], sa[a][tt], 0, 0, 0);
                sa[a][tt] = __builtin_amdgcn_mfma_f32_16x16x32_bf16(
                    kf1, qf[a][1], sa[a][tt], 0, 0, 0);
            }
        }
        __builtin_amdgcn_s_setprio(0);

        bf16x8 pf[2][2];
        #pragma unroll
        for (int a = 0; a < 2; ++a) {
            floatx4 pe[4];
            #pragma unroll
            for (int tt = 0; tt < 4; ++tt) {
                #pragma unroll
                for (int r = 0; r < 4; ++r)
                    pe[tt][r] = fast_exp2(sa[a][tt][r]);
            }
            pf[a][0] = pack8v(pe[0], pe[1]);
            pf[a][1] = pack8v(pe[2], pe[3]);
        }

        __builtin_amdgcn_s_setprio(1);
        // row-sum of P via MFMA (replaces 32 serial f32 adds per lane)
        #pragma unroll
        for (int a = 0; a < 2; ++a) {
            ls[a] = __builtin_amdgcn_mfma_f32_16x16x32_bf16(
                onesA, pf[a][0], ls[a], 0, 0, 0);
            ls[a] = __builtin_amdgcn_mfma_f32_16x16x32_bf16(
                onesA, pf[a][1], ls[a], 0, 0, 0);
        }
        #pragma unroll
        for (int jd = 0; jd < 4; ++jd) {
            const unsigned short* vb = &Vs[(jd * 16 + l15) * 64];
            bf16x8 vf0 = *(const bf16x8*)&vb[cbase];
            bf16x8 vf1 = *(const bf16x8*)&vb[cbase ^ 32];
            #pragma unroll
            for (int a = 0; a < 2; ++a) {
                oa[a][jd] = __builtin_amdgcn_mfma_f32_16x16x32_bf16(
                    vf0, pf[a][0], oa[a][jd], 0, 0, 0);
                oa[a][jd] = __builtin_amdgcn_mfma_f32_16x16x32_bf16(
                    vf1, pf[a][1], oa[a][jd], 0, 0, 0);
            }
        }
        __builtin_amdgcn_s_setprio(0);
    }

    const int b = bh >> 4, h = bh & 15;
    #pragma unroll
    for (int a = 0; a < 2; ++a) {
        float inv = 1.f / ls[a][0];   // every row of ls holds the full sum
        int n = q0 + a * 16 + l15;
        size_t base = (size_t)(b * NN + n) * EE + h * DD;
        #pragma unroll
        for (int jd = 0; jd < 4; ++jd) {
            bf16x4 v;
            v[0] = (short)f2bf(oa[a][jd][0] * inv);
            v[1] = (short)f2bf(oa[a][jd][1] * inv);
            v[2] = (short)f2bf(oa[a][jd][2] * inv);
            v[3] = (short)f2bf(oa[a][jd][3] * inv);
            *(bf16x4*)&O[base + jd * 16 + quad * 4] = v;
        }
    }
}

// ---------------------------------------------------------------------------
// Kernel 3: out = O @ Wp^T + b — same 256^2 pipelined structure, fp32 out.
// ---------------------------------------------------------------------------
__global__ __launch_bounds__(512, 2) void gemm_proj_mfma(
    const unsigned short* __restrict__ Ob,
    const unsigned short* __restrict__ Bp,
    const float* __restrict__ bias, float* __restrict__ out)
{
    __shared__ __align__(16) unsigned short As[4][256 * 32];
    __shared__ __align__(16) unsigned short Bs[4][256 * 32];

    const int t = threadIdx.x;
    const int w = t >> 6, lane = t & 63;
    const int quad = lane >> 4, l15 = lane & 15;
    const int wm = w >> 2, wn = w & 3;

    const int id  = blockIdx.x;
    const int sid = (id & 7) * ((int)gridDim.x >> 3) + (id >> 3);
    const int m0 = (sid / 4) * 256;
    const int n0 = (sid % 4) * 256;

    const int srow = lane >> 2;
    const int scw = (((lane & 3) ^ ((srow ^ (srow >> 2)) & 3))) * 8;
    const int rsw = ((quad ^ ((l15 ^ (l15 >> 2)) & 3))) * 8;

    const unsigned short* aG = &Ob[(size_t)(m0 + w * 16 + srow) * EE + scw];
    const unsigned short* bG = &Bp[(size_t)(n0 + w * 16 + srow) * EE + scw];
    const int ldsW = (w * 16) * 32;

#define STG_A(c) do { const int sl_ = (c) & 3;                          \
    ASYNC16(aG + (c) * 32,            &As[sl_][ldsW]);                  \
    ASYNC16(aG + (c) * 32 + 128 * EE, &As[sl_][ldsW + 128 * 32]); } while (0)
#define STG_B(c) do { const int sl_ = (c) & 3;                          \
    ASYNC16(bG + (c) * 32,            &Bs[sl_][ldsW]);                  \
    ASYNC16(bG + (c) * 32 + 128 * EE, &Bs[sl_][ldsW + 128 * 32]); } while (0)

    floatx4 acc[8][4];
    #pragma unroll
    for (int i = 0; i < 8; ++i)
        #pragma unroll
        for (int j = 0; j < 4; ++j) acc[i][j] = (floatx4){0.f, 0.f, 0.f, 0.f};

    STG_A(0); STG_B(0); STG_A(1); STG_B(1); STG_A(2); STG_B(2);
    __asm__ __volatile__("s_waitcnt vmcnt(8)" ::: "memory");
    __builtin_amdgcn_s_barrier();

    #pragma unroll 1
    for (int c = 0; c < GNT; ++c) {
        const unsigned short* Asl = As[c & 3];
        const unsigned short* Bsl = Bs[c & 3];
        bf16x8 bfr[4], afr[4];

        #pragma unroll
        for (int j = 0; j < 4; ++j)
            bfr[j] = *(const bf16x8*)&Bsl[(wn * 64 + j * 16 + l15) * 32 + rsw];
        #pragma unroll
        for (int i = 0; i < 4; ++i)
            afr[i] = *(const bf16x8*)&Asl[(wm * 128 + i * 16 + l15) * 32 + rsw];
        if (c + 3 < GNT) STG_A(c + 3);
        __builtin_amdgcn_s_barrier();
        __asm__ __volatile__("s_waitcnt lgkmcnt(0)" ::: "memory");
        __builtin_amdgcn_s_setprio(1);
        #pragma unroll
        for (int i = 0; i < 4; ++i)
            #pragma unroll
            for (int j = 0; j < 4; ++j)
                acc[i][j] = __builtin_amdgcn_mfma_f32_16x16x32_bf16(
                    afr[i], bfr[j], acc[i][j], 0, 0, 0);
        __builtin_amdgcn_s_setprio(0);
        __builtin_amdgcn_s_barrier();

        #pragma unroll
        for (int i = 0; i < 4; ++i)
            afr[i] = *(const bf16x8*)&Asl[(wm * 128 + 64 + i * 16 + l15) * 32 + rsw];
        if (c + 3 < GNT) STG_B(c + 3);
        __builtin_amdgcn_s_barrier();
        __asm__ __volatile__("s_waitcnt lgkmcnt(0)" ::: "memory");
        __builtin_amdgcn_s_setprio(1);
        #pragma unroll
        for (int i = 0; i < 4; ++i)
            #pragma unroll
            for (int j = 0; j < 4; ++j)
                acc[4 + i][j] = __builtin_amdgcn_mfma_f32_16x16x32_bf16(
                    afr[i], bfr[j], acc[4 + i][j], 0, 0, 0);
        __builtin_amdgcn_s_setprio(0);
        if (c < GNT - 3)       { __asm__ __volatile__("s_waitcnt vmcnt(8)" ::: "memory"); }
        else if (c == GNT - 3) { __asm__ __volatile__("s_waitcnt vmcnt(4)" ::: "memory"); }
        else if (c == GNT - 2) { __asm__ __volatile__("s_waitcnt vmcnt(0)" ::: "memory"); }
        __builtin_amdgcn_s_barrier();
    }
#undef STG_A
#undef STG_B

    const int mb = m0 + wm * 128;
    const int nbase = n0 + wn * 64;
    #pragma unroll
    for (int i = 0; i < 8; ++i) {
        #pragma unroll
        for (int j = 0; j < 4; ++j) {
            float bv = bias[nbase + j * 16 + l15];
            #pragma unroll
            for (int r = 0; r < 4; ++r) {
                int mrow = mb + i * 16 + quad * 4 + r;
                out[(size_t)mrow * EE + nbase + j * 16 + l15] = acc[i][j][r] + bv;
            }
        }
    }
}

// ---------------------------------------------------------------------------
extern "C" void kernel_launch(void* const* d_in, const int* in_sizes, int n_in,
                              void* d_out, int out_size, void* d_ws, size_t ws_size,
                              hipStream_t stream) {
    const float* x     = (const float*)d_in[0];
    const float* Wqkv  = (const float*)d_in[1];
    const float* bqkv  = (const float*)d_in[2];
    const float* Wproj = (const float*)d_in[3];
    const float* bproj = (const float*)d_in[4];
    float* out = (float*)d_out;

    const size_t BHND = (size_t)BB * HH * NN * DD;      // 16777216
    unsigned short* Q   = (unsigned short*)d_ws;
    unsigned short* K   = Q   + BHND;
    unsigned short* Vn  = K   + BHND;                   // V natural [B,H,N,D]
    unsigned short* Vt  = Vn  + BHND;                   // V^T [B,H,D,N]
    unsigned short* Ob  = Vt  + BHND;                   // [16384][1024] bf16
    unsigned short* xb  = Ob  + BHND;
    unsigned short* Wqt = xb  + BHND;                   // [3072][1024]
    unsigned short* Wpt = Wqt + (size_t)THREE_E * EE;   // [1024][1024]

    dim3 blk(256);
    convert_x<<<dim3(M_TOTAL * EE / (256 * 8)), blk, 0, stream>>>(x, xb);
    wtrans<<<dim3(THREE_E / 32, EE / 32), blk, 0, stream>>>(Wqkv, Wqt, EE, THREE_E);
    wtrans<<<dim3(EE / 32, EE / 32), blk, 0, stream>>>(Wproj, Wpt, EE, EE);

    gemm_qkv_mfma<<<dim3((M_TOTAL / 256) * (THREE_E / 256)), dim3(512), 0, stream>>>(
        xb, Wqt, bqkv, Q, K, Vn);
    vtrans<<<dim3(BB * HH, NN / 64), blk, 0, stream>>>(Vn, Vt);
    attn_mfma<<<dim3(BB * HH * NN / 128), blk, 0, stream>>>(Q, K, Vt, Ob);
    gemm_proj_mfma<<<dim3((M_TOTAL / 256) * (EE / 256)), dim3(512), 0, stream>>>(
        Ob, Wpt, bproj, out);
}

// Round 3
// 404.499 us; speedup vs baseline: 1.1055x; 1.0022x over previous
//
#include <hip/hip_runtime.h>
#include <hip/hip_bf16.h>
#include <math.h>

// Problem constants
#define BB 16
#define NN 1024
#define EE 1024
#define HH 16
#define DD 64
#define THREE_E 3072
#define M_TOTAL (BB * NN)   // 16384

typedef __attribute__((ext_vector_type(8))) short bf16x8;   // 8 bf16 = 4 VGPR
typedef __attribute__((ext_vector_type(4))) short bf16x4;   // 4 bf16 = 2 VGPR
typedef __attribute__((ext_vector_type(4))) float floatx4;  // MFMA C/D

// Q pre-scale: 1/sqrt(64) * log2(e)  (scores land in exp2 domain)
#define SCALE_Q 0.18033688011112042f

static __device__ __forceinline__ unsigned short f2bf(float f) {
    union { float f; unsigned u; } x; x.f = f;
    unsigned r = x.u + 0x7fffu + ((x.u >> 16) & 1u);
    return (unsigned short)(r >> 16);
}

// raw v_exp_f32 — scores are bounded, skip OCML denormal guards
static __device__ __forceinline__ float fast_exp2(float x) {
#if __has_builtin(__builtin_amdgcn_exp2f)
    return __builtin_amdgcn_exp2f(x);
#else
    float r; __asm__("v_exp_f32 %0, %1" : "=v"(r) : "v"(x)); return r;
#endif
}

// pack 2x floatx4 -> bf16x8 via v_cvt_pk_bf16_f32 (RNE)
static __device__ __forceinline__ bf16x8 pack8v(floatx4 a, floatx4 b) {
    union { bf16x8 v; unsigned u[4]; } r;
    __hip_bfloat162 t;
    t = __float22bfloat162_rn(make_float2(a[0], a[1])); r.u[0] = *(unsigned*)&t;
    t = __float22bfloat162_rn(make_float2(a[2], a[3])); r.u[1] = *(unsigned*)&t;
    t = __float22bfloat162_rn(make_float2(b[0], b[1])); r.u[2] = *(unsigned*)&t;
    t = __float22bfloat162_rn(make_float2(b[2], b[3])); r.u[3] = *(unsigned*)&t;
    return r.v;
}
static __device__ __forceinline__ bf16x8 pack8f(float4 a, float4 b) {
    union { bf16x8 v; unsigned u[4]; } r;
    __hip_bfloat162 t;
    t = __float22bfloat162_rn(make_float2(a.x, a.y)); r.u[0] = *(unsigned*)&t;
    t = __float22bfloat162_rn(make_float2(a.z, a.w)); r.u[1] = *(unsigned*)&t;
    t = __float22bfloat162_rn(make_float2(b.x, b.y)); r.u[2] = *(unsigned*)&t;
    t = __float22bfloat162_rn(make_float2(b.z, b.w)); r.u[3] = *(unsigned*)&t;
    return r.v;
}

// async global->LDS, 16B per lane (LDS dest wave-uniform, +lane*16 implicit)
#define ASYNC16(gp, lp)                                                \
    __builtin_amdgcn_global_load_lds(                                  \
        (const __attribute__((address_space(1))) void*)(gp),           \
        (__attribute__((address_space(3))) void*)(lp), 16, 0, 0)

#define DRAIN_VMEM() __asm__ __volatile__("s_waitcnt vmcnt(0)" ::: "memory")

// ---------------------------------------------------------------------------
// Prep 1: x fp32 [M,K] -> bf16 same layout.
// ---------------------------------------------------------------------------
__global__ __launch_bounds__(256) void convert_x(
    const float* __restrict__ x, unsigned short* __restrict__ xb)
{
    int i = blockIdx.x * 256 + threadIdx.x;
    const float4* xp = (const float4*)x;
    float4 a = xp[i * 2], b = xp[i * 2 + 1];
    *(bf16x8*)&xb[i * 8] = pack8f(a, b);
}

// ---------------------------------------------------------------------------
// Prep 2: transpose-convert W [R][C] fp32 -> bf16 [C][R].
// ---------------------------------------------------------------------------
__global__ __launch_bounds__(256) void wtrans(
    const float* __restrict__ w, unsigned short* __restrict__ wt, int R, int C)
{
    __shared__ float tile[32][33];
    const int t = threadIdx.x;
    const int lr = t >> 5, lc = t & 31;
    const int r0 = blockIdx.y * 32, c0 = blockIdx.x * 32;
    #pragma unroll
    for (int p = 0; p < 4; ++p)
        tile[lr + p * 8][lc] = w[(size_t)(r0 + lr + p * 8) * C + c0 + lc];
    __syncthreads();
    #pragma unroll
    for (int p = 0; p < 4; ++p) {
        int oc = lr + p * 8;
        float v = tile[lc][oc];
        wt[(size_t)(c0 + oc) * R + r0 + lc] = f2bf(v);
    }
}

// ---------------------------------------------------------------------------
// Kernel 1: qkv = xb @ Wqkv^T + b (bf16 MFMA).
// R3: proven 128x128 skeleton (R0, 142.8us) with BK=64 (half the
// vmcnt(0)+barrier drain events; 128B-contiguous row fetches).
// Swizzle: sigma(row)=row&7 over eight 16B chunks per 128B row; every
// 8-lane b128 beat spans all 32 banks.
// ---------------------------------------------------------------------------
__global__ __launch_bounds__(256) void gemm_qkv_mfma(
    const unsigned short* __restrict__ xb,
    const unsigned short* __restrict__ wt,
    const float* __restrict__ bias,
    unsigned short* __restrict__ Qo, unsigned short* __restrict__ Ko,
    unsigned short* __restrict__ Vo)
{
    __shared__ __align__(16) unsigned short As[128 * 64];   // 16 KB
    __shared__ __align__(16) unsigned short Bs[128 * 64];   // 16 KB

    const int t = threadIdx.x;
    const int w = t >> 6, lane = t & 63;
    const int quad = lane >> 4, l15 = lane & 15;
    const int wm = w >> 1, wn = w & 1;
    const int m0 = blockIdx.y * 128;
    const int n0 = blockIdx.x * 128;
    const int srow = lane >> 3;            // 0..7: row within 8-row stripe
    const int sch  = lane & 7;             // 16B chunk slot within 128B row
    const int scw  = (sch ^ srow) * 8;     // swizzled global k-chunk (elems)
    const int rb   = l15 & 7;              // read swizzle base (= row&7)

    floatx4 acc[4][4];
    #pragma unroll
    for (int i = 0; i < 4; ++i)
        #pragma unroll
        for (int j = 0; j < 4; ++j) acc[i][j] = (floatx4){0.f, 0.f, 0.f, 0.f};

    const unsigned short* aG = &xb[(size_t)(m0 + w * 8 + srow) * EE + scw];
    const unsigned short* bG = &wt[(size_t)(n0 + w * 8 + srow) * EE + scw];

    for (int kk = 0; kk < EE; kk += 64) {
        #pragma unroll
        for (int p = 0; p < 4; ++p) {
            ASYNC16(aG + kk + (size_t)(p * 32) * EE, &As[(w * 8 + p * 32) * 64]);
            ASYNC16(bG + kk + (size_t)(p * 32) * EE, &Bs[(w * 8 + p * 32) * 64]);
        }
        DRAIN_VMEM();
        __syncthreads();

        #pragma unroll
        for (int s = 0; s < 2; ++s) {
            const int rsw = (((s << 2) | quad) ^ rb) * 8;
            bf16x8 af[4], bf[4];
            #pragma unroll
            for (int i = 0; i < 4; ++i) {
                af[i] = *(const bf16x8*)&As[(wm * 64 + i * 16 + l15) * 64 + rsw];
                bf[i] = *(const bf16x8*)&Bs[(wn * 64 + i * 16 + l15) * 64 + rsw];
            }
            #pragma unroll
            for (int i = 0; i < 4; ++i)
                #pragma unroll
                for (int j = 0; j < 4; ++j)
                    acc[i][j] = __builtin_amdgcn_mfma_f32_16x16x32_bf16(
                        af[i], bf[j], acc[i][j], 0, 0, 0);
        }
        __syncthreads();
    }

    const int mb = m0 + wm * 64;
    const int nb = n0 + wn * 64;
    #pragma unroll
    for (int i = 0; i < 4; ++i) {
        #pragma unroll
        for (int j = 0; j < 4; ++j) {
            int nc = nb + j * 16;
            int which = nc >> 10;
            int e0 = nc & 1023;
            int h  = e0 >> 6;
            int d0 = e0 & 63;
            float bv = bias[nc + l15];
            #pragma unroll
            for (int r = 0; r < 4; ++r) {
                int m = mb + i * 16 + quad * 4 + r;
                int b = m >> 10, n = m & 1023;
                size_t off = ((size_t)(b * HH + h) * NN + n) * DD + d0 + l15;
                float v = acc[i][j][r] + bv;
                if (which == 0)      Qo[off] = f2bf(v * SCALE_Q);
                else if (which == 1) Ko[off] = f2bf(v);
                else                 Vo[off] = f2bf(v);
            }
        }
    }
}

// ---------------------------------------------------------------------------
// Prep 3 (post-qkv): V [B,H,N,D] bf16 -> Vt [B,H,D,N] bf16.
// ---------------------------------------------------------------------------
__global__ __launch_bounds__(256) void vtrans(
    const unsigned short* __restrict__ V, unsigned short* __restrict__ Vt)
{
    __shared__ __align__(16) unsigned short tile[64][72];   // [d][n]
    const int t  = threadIdx.x;
    const int bh = blockIdx.x;       // 0..255
    const int n0 = blockIdx.y * 64;  // 16 tiles
    const int r  = t >> 2, c = t & 3;

    const unsigned short* src = &V[((size_t)bh * NN + n0 + r) * DD + c * 16];
    bf16x8 v0 = *(const bf16x8*)&src[0];
    bf16x8 v1 = *(const bf16x8*)&src[8];
    #pragma unroll
    for (int k = 0; k < 8; ++k) tile[c * 16 + k][r]     = v0[k];
    #pragma unroll
    for (int k = 0; k < 8; ++k) tile[c * 16 + 8 + k][r] = v1[k];
    __syncthreads();

    unsigned short* dst = &Vt[((size_t)bh * DD + r) * NN + n0 + c * 16];
    *(bf16x8*)&dst[0] = *(const bf16x8*)&tile[r][c * 16];
    *(bf16x8*)&dst[8] = *(const bf16x8*)&tile[r][c * 16 + 8];
}

// ---------------------------------------------------------------------------
// Kernel 2: transposed-score flash attention, bf16 MFMA (unchanged from R2:
// raw v_exp_f32, MFMA-ones row-sum, setprio around MFMA clusters).
// ---------------------------------------------------------------------------
__global__ __launch_bounds__(256) void attn_mfma(
    const unsigned short* __restrict__ Q,
    const unsigned short* __restrict__ K,
    const unsigned short* __restrict__ Vt,
    unsigned short* __restrict__ O)
{
    __shared__ __align__(16) unsigned short Ks[64 * 64];  // [key][d], swizzled
    __shared__ __align__(16) unsigned short Vs[64 * 64];  // [d][kappa], swizzled

    const int t    = threadIdx.x;
    const int w    = t >> 6;
    const int quad = (t >> 4) & 3;
    const int l15  = t & 15;
    const int i    = blockIdx.x;                 // 0..2047
    const int bh   = ((i >> 6) << 3) | (i & 7);  // XCD-local bh windows
    const int qt   = (i >> 3) & 7;

    const unsigned short* Qg = Q  + (size_t)bh * NN * DD;
    const unsigned short* Kg = K  + (size_t)bh * NN * DD;
    const unsigned short* Vg = Vt + (size_t)bh * DD * NN;

    const int q0 = qt * 128 + w * 32;

    bf16x8 qf[2][2];
    #pragma unroll
    for (int a = 0; a < 2; ++a) {
        qf[a][0] = *(const bf16x8*)&Qg[(size_t)(q0 + a * 16 + l15) * DD + quad * 8];
        qf[a][1] = *(const bf16x8*)&Qg[(size_t)(q0 + a * 16 + l15) * DD + 32 + quad * 8];
    }

    // all-ones A-fragment: mfma(ones, P) -> every output element = column sum
    bf16x8 onesA;
    #pragma unroll
    for (int z = 0; z < 8; ++z) onesA[z] = (short)0x3F80;  // bf16 1.0

    floatx4 oa[2][4];
    #pragma unroll
    for (int a = 0; a < 2; ++a)
        #pragma unroll
        for (int jd = 0; jd < 4; ++jd) oa[a][jd] = (floatx4){0.f, 0.f, 0.f, 0.f};
    floatx4 ls[2];
    ls[0] = (floatx4){0.f, 0.f, 0.f, 0.f};
    ls[1] = (floatx4){0.f, 0.f, 0.f, 0.f};

    const int srow = t >> 2;
    const int sc   = t & 3;
    const int swz  = srow & 7;
    const int cbase = ((quad ^ (l15 & 7)) << 3);

    bf16x8 kr0, kr1, vr0, vr1;
    {
        const unsigned short* kg = &Kg[(size_t)srow * DD + sc * 16];
        kr0 = *(const bf16x8*)&kg[0];
        kr1 = *(const bf16x8*)&kg[8];
        const unsigned short* vg = &Vg[(size_t)srow * NN + sc * 16];
        vr0 = *(const bf16x8*)&vg[0];
        vr1 = *(const bf16x8*)&vg[8];
    }

    for (int kt = 0; kt < 16; ++kt) {
        __syncthreads();
        *(bf16x8*)&Ks[srow * 64 + (((2 * sc + 0) ^ swz) << 3)] = kr0;
        *(bf16x8*)&Ks[srow * 64 + (((2 * sc + 1) ^ swz) << 3)] = kr1;
        {
            bf16x4 h[4];
            h[0] = (bf16x4){vr0[0], vr0[1], vr0[2], vr0[3]};
            h[1] = (bf16x4){vr0[4], vr0[5], vr0[6], vr0[7]};
            h[2] = (bf16x4){vr1[0], vr1[1], vr1[2], vr1[3]};
            h[3] = (bf16x4){vr1[4], vr1[5], vr1[6], vr1[7]};
            #pragma unroll
            for (int q = 0; q < 4; ++q) {
                int col = ((((sc >> 1) * 4 + q) ^ swz) << 3) + ((sc & 1) << 2);
                *(bf16x4*)&Vs[srow * 64 + col] = h[q];
            }
        }
        __syncthreads();

        if (kt < 15) {
            const unsigned short* kg =
                &Kg[(size_t)((kt + 1) * 64 + srow) * DD + sc * 16];
            kr0 = *(const bf16x8*)&kg[0];
            kr1 = *(const bf16x8*)&kg[8];
            const unsigned short* vg =
                &Vg[(size_t)srow * NN + (kt + 1) * 64 + sc * 16];
            vr0 = *(const bf16x8*)&vg[0];
            vr1 = *(const bf16x8*)&vg[8];
        }

        floatx4 sa[2][4];
        #pragma unroll
        for (int a = 0; a < 2; ++a)
            #pragma unroll
            for (int tt = 0; tt < 4; ++tt) sa[a][tt] = (floatx4){0.f, 0.f, 0.f, 0.f};
        __builtin_amdgcn_s_setprio(1);
        #pragma unroll
        for (int tt = 0; tt < 4; ++tt) {
            const unsigned short* kb = &Ks[(tt * 16 + l15) * 64];
            bf16x8 kf0 = *(const bf16x8*)&kb[cbase];
            bf16x8 kf1 = *(const bf16x8*)&kb[cbase ^ 32];
            #pragma unroll
            for (int a = 0; a < 2; ++a) {
                sa[a][tt] = __builtin_amdgcn_mfma_f32_16x16x32_bf16(
                    kf0, qf[a][0], sa[a][tt], 0, 0, 0);
                sa[a][tt] = __builtin_amdgcn_mfma_f32_16x16x32_bf16(
                    kf1, qf[a][1], sa[a][tt], 0, 0, 0);
            }
        }
        __builtin_amdgcn_s_setprio(0);

        bf16x8 pf[2][2];
        #pragma unroll
        for (int a = 0; a < 2; ++a) {
            floatx4 pe[4];
            #pragma unroll
            for (int tt = 0; tt < 4; ++tt) {
                #pragma unroll
                for (int r = 0; r < 4; ++r)
                    pe[tt][r] = fast_exp2(sa[a][tt][r]);
            }
            pf[a][0] = pack8v(pe[0], pe[1]);
            pf[a][1] = pack8v(pe[2], pe[3]);
        }

        __builtin_amdgcn_s_setprio(1);
        // row-sum of P via MFMA (replaces 32 serial f32 adds per lane)
        #pragma unroll
        for (int a = 0; a < 2; ++a) {
            ls[a] = __builtin_amdgcn_mfma_f32_16x16x32_bf16(
                onesA, pf[a][0], ls[a], 0, 0, 0);
            ls[a] = __builtin_amdgcn_mfma_f32_16x16x32_bf16(
                onesA, pf[a][1], ls[a], 0, 0, 0);
        }
        #pragma unroll
        for (int jd = 0; jd < 4; ++jd) {
            const unsigned short* vb = &Vs[(jd * 16 + l15) * 64];
            bf16x8 vf0 = *(const bf16x8*)&vb[cbase];
            bf16x8 vf1 = *(const bf16x8*)&vb[cbase ^ 32];
            #pragma unroll
            for (int a = 0; a < 2; ++a) {
                oa[a][jd] = __builtin_amdgcn_mfma_f32_16x16x32_bf16(
                    vf0, pf[a][0], oa[a][jd], 0, 0, 0);
                oa[a][jd] = __builtin_amdgcn_mfma_f32_16x16x32_bf16(
                    vf1, pf[a][1], oa[a][jd], 0, 0, 0);
            }
        }
        __builtin_amdgcn_s_setprio(0);
    }

    const int b = bh >> 4, h = bh & 15;
    #pragma unroll
    for (int a = 0; a < 2; ++a) {
        float inv = 1.f / ls[a][0];   // every row of ls holds the full sum
        int n = q0 + a * 16 + l15;
        size_t base = (size_t)(b * NN + n) * EE + h * DD;
        #pragma unroll
        for (int jd = 0; jd < 4; ++jd) {
            bf16x4 v;
            v[0] = (short)f2bf(oa[a][jd][0] * inv);
            v[1] = (short)f2bf(oa[a][jd][1] * inv);
            v[2] = (short)f2bf(oa[a][jd][2] * inv);
            v[3] = (short)f2bf(oa[a][jd][3] * inv);
            *(bf16x4*)&O[base + jd * 16 + quad * 4] = v;
        }
    }
}

// ---------------------------------------------------------------------------
// Kernel 3: out = O @ Wp^T + b — 128x128, BK=64, fp32 out.
// ---------------------------------------------------------------------------
__global__ __launch_bounds__(256) void gemm_proj_mfma(
    const unsigned short* __restrict__ Ob,
    const unsigned short* __restrict__ Bp,
    const float* __restrict__ bias, float* __restrict__ out)
{
    __shared__ __align__(16) unsigned short As[128 * 64];
    __shared__ __align__(16) unsigned short Bs[128 * 64];

    const int t = threadIdx.x;
    const int w = t >> 6, lane = t & 63;
    const int quad = lane >> 4, l15 = lane & 15;
    const int wm = w >> 1, wn = w & 1;
    const int m0 = blockIdx.y * 128;
    const int n0 = blockIdx.x * 128;
    const int srow = lane >> 3;
    const int sch  = lane & 7;
    const int scw  = (sch ^ srow) * 8;
    const int rb   = l15 & 7;

    floatx4 acc[4][4];
    #pragma unroll
    for (int i = 0; i < 4; ++i)
        #pragma unroll
        for (int j = 0; j < 4; ++j) acc[i][j] = (floatx4){0.f, 0.f, 0.f, 0.f};

    const unsigned short* aG = &Ob[(size_t)(m0 + w * 8 + srow) * EE + scw];
    const unsigned short* bG = &Bp[(size_t)(n0 + w * 8 + srow) * EE + scw];

    for (int kk = 0; kk < EE; kk += 64) {
        #pragma unroll
        for (int p = 0; p < 4; ++p) {
            ASYNC16(aG + kk + (size_t)(p * 32) * EE, &As[(w * 8 + p * 32) * 64]);
            ASYNC16(bG + kk + (size_t)(p * 32) * EE, &Bs[(w * 8 + p * 32) * 64]);
        }
        DRAIN_VMEM();
        __syncthreads();

        #pragma unroll
        for (int s = 0; s < 2; ++s) {
            const int rsw = (((s << 2) | quad) ^ rb) * 8;
            bf16x8 af[4], bf[4];
            #pragma unroll
            for (int i = 0; i < 4; ++i) {
                af[i] = *(const bf16x8*)&As[(wm * 64 + i * 16 + l15) * 64 + rsw];
                bf[i] = *(const bf16x8*)&Bs[(wn * 64 + i * 16 + l15) * 64 + rsw];
            }
            #pragma unroll
            for (int i = 0; i < 4; ++i)
                #pragma unroll
                for (int j = 0; j < 4; ++j)
                    acc[i][j] = __builtin_amdgcn_mfma_f32_16x16x32_bf16(
                        af[i], bf[j], acc[i][j], 0, 0, 0);
        }
        __syncthreads();
    }

    const int mb = m0 + wm * 64;
    const int nb = n0 + wn * 64;
    #pragma unroll
    for (int i = 0; i < 4; ++i) {
        #pragma unroll
        for (int j = 0; j < 4; ++j) {
            float bv = bias[nb + j * 16 + l15];
            #pragma unroll
            for (int r = 0; r < 4; ++r) {
                int mrow = mb + i * 16 + quad * 4 + r;
                out[(size_t)mrow * EE + nb + j * 16 + l15] = acc[i][j][r] + bv;
            }
        }
    }
}

// ---------------------------------------------------------------------------
extern "C" void kernel_launch(void* const* d_in, const int* in_sizes, int n_in,
                              void* d_out, int out_size, void* d_ws, size_t ws_size,
                              hipStream_t stream) {
    const float* x     = (const float*)d_in[0];
    const float* Wqkv  = (const float*)d_in[1];
    const float* bqkv  = (const float*)d_in[2];
    const float* Wproj = (const float*)d_in[3];
    const float* bproj = (const float*)d_in[4];
    float* out = (float*)d_out;

    const size_t BHND = (size_t)BB * HH * NN * DD;      // 16777216
    unsigned short* Q   = (unsigned short*)d_ws;
    unsigned short* K   = Q   + BHND;
    unsigned short* Vn  = K   + BHND;                   // V natural [B,H,N,D]
    unsigned short* Vt  = Vn  + BHND;                   // V^T [B,H,D,N]
    unsigned short* Ob  = Vt  + BHND;                   // [16384][1024] bf16
    unsigned short* xb  = Ob  + BHND;
    unsigned short* Wqt = xb  + BHND;                   // [3072][1024]
    unsigned short* Wpt = Wqt + (size_t)THREE_E * EE;   // [1024][1024]

    dim3 blk(256);
    convert_x<<<dim3(M_TOTAL * EE / (256 * 8)), blk, 0, stream>>>(x, xb);
    wtrans<<<dim3(THREE_E / 32, EE / 32), blk, 0, stream>>>(Wqkv, Wqt, EE, THREE_E);
    wtrans<<<dim3(EE / 32, EE / 32), blk, 0, stream>>>(Wproj, Wpt, EE, EE);

    gemm_qkv_mfma<<<dim3(THREE_E / 128, M_TOTAL / 128), blk, 0, stream>>>(
        xb, Wqt, bqkv, Q, K, Vn);
    vtrans<<<dim3(BB * HH, NN / 64), blk, 0, stream>>>(Vn, Vt);
    attn_mfma<<<dim3(BB * HH * NN / 128), blk, 0, stream>>>(Q, K, Vt, Ob);
    gemm_proj_mfma<<<dim3(EE / 128, M_TOTAL / 128), blk, 0, stream>>>(
        Ob, Wpt, bproj, out);
}